// Round 1
// baseline (795.266 us; speedup 1.0000x reference)
//
#include <hip/hip_runtime.h>
#include <stdint.h>

// ---- problem constants ----
#define NWINDOWS 2048          // B*N_WIN = 32*64
#define NROWS    131072        // NWINDOWS*64 tokens
// qkv row layout: [768] = q(0:256) k(256:512) v(512:768)

typedef short bf16x8 __attribute__((ext_vector_type(8)));
typedef float f32x4  __attribute__((ext_vector_type(4)));

// workspace layout (bytes)
#define OFF_WQKV  0u           // 768*256 bf16  = 393216
#define OFF_WPROJ 393216u      // 256*256 bf16  = 131072
#define OFF_BQKV  524288u      // 768 f32       = 3072
#define OFF_BIAS  527360u      // 32*64*64 f32  = 524288
#define OFF_QKV   1051648u     // 131072*768 bf16 = 201326592
#define WS_NEED   202378240u

__device__ __forceinline__ unsigned short f2bf(float f) {
    union { float f; unsigned int u; } v; v.f = f;
    unsigned int u = v.u;
    u += 0x7FFFu + ((u >> 16) & 1u);     // RNE
    return (unsigned short)(u >> 16);
}

// ---------------- K0: prep (weights->bf16, fold q-scale, bias table) --------
__global__ __launch_bounds__(256)
void prep_kernel(const float* __restrict__ qkv_w, const float* __restrict__ qkv_b,
                 const float* __restrict__ proj_w, const float* __restrict__ theta_max,
                 const float* __restrict__ a_p, const float* __restrict__ b_p,
                 const float* __restrict__ a_r, const float* __restrict__ b_r,
                 const int* __restrict__ radius, const int* __restrict__ azimuth,
                 unsigned short* __restrict__ w_qkv, unsigned short* __restrict__ w_proj,
                 float* __restrict__ b_qkv, float* __restrict__ bias_tbl)
{
    int idx = blockIdx.x * 256 + threadIdx.x;
    const float scale = 0.0625f;                    // head_dim^-0.5 = 1/16
    if (idx < 196608) {                             // qkv_w -> bf16 (q rows scaled)
        int row = idx >> 8;
        float v = qkv_w[idx];
        if (row < 256) v *= scale;
        w_qkv[idx] = f2bf(v);
    } else if (idx < 196608 + 65536) {              // proj_w -> bf16
        int j = idx - 196608;
        w_proj[j] = f2bf(proj_w[j]);
    } else if (idx < 196608 + 65536 + 768) {        // qkv_b (scaled), kept f32
        int j = idx - (196608 + 65536);
        float v = qkv_b[j];
        if (j < 256) v *= scale;
        b_qkv[j] = v;
    } else if (idx < 196608 + 65536 + 768 + 131072) {  // bias_tbl[32][64][64]
        int j = idx - (196608 + 65536 + 768);
        int b  = j >> 12;
        int ij = j & 4095;
        int az = azimuth[ij];
        int rd = radius[ij];
        int aidx = az < 0 ? az + 15 : az;
        int ridx = rd < 0 ? rd + 15 : rd;
        float azf = (float)az * 0.09817477042468103f;   // 2*pi/64
        float phi = a_p[aidx] * cosf(azf) + b_p[aidx] * sinf(azf);
        float rn  = (float)rd * theta_max[b] * 0.015625f; // /64
        bias_tbl[j] = phi + a_r[ridx] * cosf(rn) + b_r[ridx] * sinf(rn);
    }
}

// ---------------- K1: QKV GEMM  [131072,256]x[256,768] -> bf16 qkv ----------
__global__ __launch_bounds__(256)
void qkv_gemm(const float* __restrict__ x, const unsigned short* __restrict__ w_qkv,
              const float* __restrict__ b_qkv, unsigned short* __restrict__ qkv)
{
    const int w    = threadIdx.x >> 6;
    const int lane = threadIdx.x & 63;
    const int quad = lane >> 4;
    const int l16  = lane & 15;
    const int mbase = blockIdx.x * 64 + w * 16;

    // preload + convert 8 A-frags (this lane's row, full K=256)
    bf16x8 afrag[8];
    const float* xrow = x + (size_t)(mbase + l16) * 256;
    #pragma unroll
    for (int kk = 0; kk < 8; ++kk) {
        const float4* p = (const float4*)(xrow + kk * 32 + quad * 8);
        float4 v0 = p[0], v1 = p[1];
        bf16x8 a;
        a[0] = (short)f2bf(v0.x); a[1] = (short)f2bf(v0.y);
        a[2] = (short)f2bf(v0.z); a[3] = (short)f2bf(v0.w);
        a[4] = (short)f2bf(v1.x); a[5] = (short)f2bf(v1.y);
        a[6] = (short)f2bf(v1.z); a[7] = (short)f2bf(v1.w);
        afrag[kk] = a;
    }

    for (int nt = 0; nt < 48; ++nt) {               // 768 cols / 16
        int ncol = nt * 16 + l16;
        const unsigned short* wp = w_qkv + ncol * 256 + quad * 8;
        f32x4 c = {0.f, 0.f, 0.f, 0.f};
        #pragma unroll
        for (int kk = 0; kk < 8; ++kk) {
            bf16x8 b = *(const bf16x8*)(wp + kk * 32);
            c = __builtin_amdgcn_mfma_f32_16x16x32_bf16(afrag[kk], b, c, 0, 0, 0);
        }
        float bias = b_qkv[ncol];
        #pragma unroll
        for (int r = 0; r < 4; ++r)
            qkv[(size_t)(mbase + quad * 4 + r) * 768 + ncol] = f2bf(c[r] + bias);
    }
}

// ---------------- K2: per-window attention ----------------------------------
// S = Q K^T (+bias), softmax in regs, P via LDS, out = P V written over q-slot
__global__ __launch_bounds__(256)
void attn_kernel(const float* __restrict__ bias_tbl, unsigned short* __restrict__ qkv)
{
    __shared__ unsigned short vT[256 * 64];   // [dim][tok], 16B-chunk XOR swizzled
    __shared__ unsigned short Pl[64 * 72];    // [row][col+pad8]

    const int win   = blockIdx.x;
    const int batch = win >> 6;
    const size_t rowbase = (size_t)win * 64;
    const int tid  = threadIdx.x;
    const int w    = tid >> 6;
    const int lane = tid & 63;
    const int quad = lane >> 4;
    const int l16  = lane & 15;

    // ---- stage V transposed + swizzled: thread = (tok, dim-group of 64) ----
    {
        int tok = tid >> 2;
        int dg  = tid & 3;
        const unsigned short* src = qkv + (rowbase + tok) * 768 + 512 + dg * 64;
        #pragma unroll
        for (int jc = 0; jc < 8; ++jc) {
            bf16x8 v8 = *(const bf16x8*)(src + jc * 8);
            #pragma unroll
            for (int e = 0; e < 8; ++e) {
                int d   = dg * 64 + jc * 8 + e;
                int swz = (((tok >> 3) ^ (d & 7)) << 3) | (tok & 7);
                vT[d * 64 + swz] = (unsigned short)v8[e];
            }
        }
    }

    // ---- preload Q frags (q already scaled by 1/16 in K1) ----
    bf16x8 qf[8];
    const unsigned short* qrow = qkv + (rowbase + w * 16 + l16) * 768;
    #pragma unroll
    for (int kk = 0; kk < 8; ++kk)
        qf[kk] = *(const bf16x8*)(qrow + kk * 32 + quad * 8);

    // ---- S = Q K^T : wave w owns rows [w*16, w*16+16), 4 col-tiles ----
    f32x4 S[4];
    #pragma unroll
    for (int t = 0; t < 4; ++t) {
        const unsigned short* krow = qkv + (rowbase + t * 16 + l16) * 768 + 256 + quad * 8;
        f32x4 c = {0.f, 0.f, 0.f, 0.f};
        #pragma unroll
        for (int kk = 0; kk < 8; ++kk) {
            bf16x8 b = *(const bf16x8*)(krow + kk * 32);
            c = __builtin_amdgcn_mfma_f32_16x16x32_bf16(qf[kk], b, c, 0, 0, 0);
        }
        S[t] = c;
    }

    // ---- bias add (combined phi + theta table) ----
    const float* bt = bias_tbl + batch * 4096 + (w * 16 + quad * 4) * 64 + l16;
    #pragma unroll
    for (int t = 0; t < 4; ++t)
        #pragma unroll
        for (int r = 0; r < 4; ++r)
            S[t][r] += bt[r * 64 + t * 16];

    // ---- softmax per row, fully in registers (16-lane quad reduction) ----
    float inv[4];
    #pragma unroll
    for (int r = 0; r < 4; ++r) {
        float m = fmaxf(fmaxf(S[0][r], S[1][r]), fmaxf(S[2][r], S[3][r]));
        #pragma unroll
        for (int off = 1; off < 16; off <<= 1)
            m = fmaxf(m, __shfl_xor(m, off, 64));
        float s = 0.f;
        #pragma unroll
        for (int t = 0; t < 4; ++t) { S[t][r] = __expf(S[t][r] - m); s += S[t][r]; }
        #pragma unroll
        for (int off = 1; off < 16; off <<= 1)
            s += __shfl_xor(s, off, 64);
        inv[r] = 1.0f / s;
    }

    // ---- P -> LDS (A-operand layout source) ----
    #pragma unroll
    for (int t = 0; t < 4; ++t)
        #pragma unroll
        for (int r = 0; r < 4; ++r)
            Pl[(w * 16 + quad * 4 + r) * 72 + t * 16 + l16] = f2bf(S[t][r] * inv[r]);

    __syncthreads();   // vT staged by all, P by own wave

    // ---- out = P V, write bf16 over the q slot (own rows only) ----
    #pragma unroll
    for (int n = 0; n < 16; ++n) {
        f32x4 c = {0.f, 0.f, 0.f, 0.f};
        int dim = n * 16 + l16;
        #pragma unroll
        for (int kk = 0; kk < 2; ++kk) {
            bf16x8 a = *(const bf16x8*)(&Pl[(w * 16 + l16) * 72 + kk * 32 + quad * 8]);
            int chunk = (kk * 4 + quad) ^ (dim & 7);
            bf16x8 b = *(const bf16x8*)(&vT[dim * 64 + chunk * 8]);
            c = __builtin_amdgcn_mfma_f32_16x16x32_bf16(a, b, c, 0, 0, 0);
        }
        #pragma unroll
        for (int r = 0; r < 4; ++r)
            qkv[(rowbase + w * 16 + quad * 4 + r) * 768 + dim] = f2bf(c[r]);
    }
}

// ---------------- K3: proj GEMM [131072,256]x[256,256] + bias -> f32 --------
__global__ __launch_bounds__(256)
void proj_gemm(const unsigned short* __restrict__ qkv, const unsigned short* __restrict__ w_proj,
               const float* __restrict__ proj_b, float* __restrict__ out)
{
    const int w    = threadIdx.x >> 6;
    const int lane = threadIdx.x & 63;
    const int quad = lane >> 4;
    const int l16  = lane & 15;
    const int mbase = blockIdx.x * 64 + w * 16;

    bf16x8 afrag[8];
    const unsigned short* arow = qkv + (size_t)(mbase + l16) * 768 + quad * 8;
    #pragma unroll
    for (int kk = 0; kk < 8; ++kk)
        afrag[kk] = *(const bf16x8*)(arow + kk * 32);

    for (int nt = 0; nt < 16; ++nt) {
        int ncol = nt * 16 + l16;
        const unsigned short* wp = w_proj + ncol * 256 + quad * 8;
        f32x4 c = {0.f, 0.f, 0.f, 0.f};
        #pragma unroll
        for (int kk = 0; kk < 8; ++kk) {
            bf16x8 b = *(const bf16x8*)(wp + kk * 32);
            c = __builtin_amdgcn_mfma_f32_16x16x32_bf16(afrag[kk], b, c, 0, 0, 0);
        }
        float pb = proj_b[ncol];
        #pragma unroll
        for (int r = 0; r < 4; ++r)
            out[(size_t)(mbase + quad * 4 + r) * 256 + ncol] = c[r] + pb;
    }
}

// ---------------- launch ----------------------------------------------------
extern "C" void kernel_launch(void* const* d_in, const int* in_sizes, int n_in,
                              void* d_out, int out_size, void* d_ws, size_t ws_size,
                              hipStream_t stream)
{
    const float* x       = (const float*)d_in[0];
    const float* theta   = (const float*)d_in[1];
    const float* qkv_w   = (const float*)d_in[2];
    const float* qkv_b   = (const float*)d_in[3];
    const float* proj_w  = (const float*)d_in[4];
    const float* proj_b  = (const float*)d_in[5];
    const float* a_p     = (const float*)d_in[6];
    const float* b_p     = (const float*)d_in[7];
    const float* a_r     = (const float*)d_in[8];
    const float* b_r     = (const float*)d_in[9];
    const int*   radius  = (const int*)d_in[10];
    const int*   azimuth = (const int*)d_in[11];

    if (ws_size < (size_t)WS_NEED) return;   // workspace too small: fail loudly (wrong answer)

    char* ws = (char*)d_ws;
    unsigned short* w_qkv  = (unsigned short*)(ws + OFF_WQKV);
    unsigned short* w_proj = (unsigned short*)(ws + OFF_WPROJ);
    float*          b_qkv  = (float*)(ws + OFF_BQKV);
    float*          bias_tbl = (float*)(ws + OFF_BIAS);
    unsigned short* qkv    = (unsigned short*)(ws + OFF_QKV);

    prep_kernel<<<1540, 256, 0, stream>>>(qkv_w, qkv_b, proj_w, theta,
                                          a_p, b_p, a_r, b_r, radius, azimuth,
                                          w_qkv, w_proj, b_qkv, bias_tbl);
    qkv_gemm<<<NWINDOWS, 256, 0, stream>>>(x, w_qkv, b_qkv, qkv);
    attn_kernel<<<NWINDOWS, 256, 0, stream>>>(bias_tbl, qkv);
    proj_gemm<<<NWINDOWS, 256, 0, stream>>>(qkv, w_proj, proj_b, (float*)d_out);
}

// Round 2
// 459.248 us; speedup vs baseline: 1.7317x; 1.7317x over previous
//
#include <hip/hip_runtime.h>
#include <stdint.h>

// ---- problem constants ----
#define NWINDOWS 2048          // B*N_WIN = 32*64
// qkv row layout: [768] = q(0:256) k(256:512) v(512:768)

typedef short bf16x8 __attribute__((ext_vector_type(8)));
typedef float f32x4  __attribute__((ext_vector_type(4)));

// workspace layout (bytes)
#define OFF_WQKV  0u           // 768*256 bf16  = 393216
#define OFF_WPROJ 393216u      // 256*256 bf16  = 131072
#define OFF_BQKV  524288u      // 768 f32       = 3072
#define OFF_BIAS  527360u      // 32*64*64 f32  = 524288
#define OFF_QKV   1051648u     // 131072*768 bf16 = 201326592
#define WS_NEED   202378240u

__device__ __forceinline__ unsigned short f2bf(float f) {
    union { float f; unsigned int u; } v; v.f = f;
    unsigned int u = v.u;
    u += 0x7FFFu + ((u >> 16) & 1u);     // RNE
    return (unsigned short)(u >> 16);
}

// ---------------- K0: prep (weights->bf16, fold q-scale, bias table) --------
__global__ __launch_bounds__(256)
void prep_kernel(const float* __restrict__ qkv_w, const float* __restrict__ qkv_b,
                 const float* __restrict__ proj_w, const float* __restrict__ theta_max,
                 const float* __restrict__ a_p, const float* __restrict__ b_p,
                 const float* __restrict__ a_r, const float* __restrict__ b_r,
                 const int* __restrict__ radius, const int* __restrict__ azimuth,
                 unsigned short* __restrict__ w_qkv, unsigned short* __restrict__ w_proj,
                 float* __restrict__ b_qkv, float* __restrict__ bias_tbl)
{
    int idx = blockIdx.x * 256 + threadIdx.x;
    const float scale = 0.0625f;                    // head_dim^-0.5 = 1/16
    if (idx < 196608) {                             // qkv_w -> bf16 (q rows scaled)
        int row = idx >> 8;
        float v = qkv_w[idx];
        if (row < 256) v *= scale;
        w_qkv[idx] = f2bf(v);
    } else if (idx < 196608 + 65536) {              // proj_w -> bf16
        int j = idx - 196608;
        w_proj[j] = f2bf(proj_w[j]);
    } else if (idx < 196608 + 65536 + 768) {        // qkv_b (scaled), kept f32
        int j = idx - (196608 + 65536);
        float v = qkv_b[j];
        if (j < 256) v *= scale;
        b_qkv[j] = v;
    } else if (idx < 196608 + 65536 + 768 + 131072) {  // bias_tbl[32][64][64]
        int j = idx - (196608 + 65536 + 768);
        int b  = j >> 12;
        int ij = j & 4095;
        int az = azimuth[ij];
        int rd = radius[ij];
        int aidx = az < 0 ? az + 15 : az;
        int ridx = rd < 0 ? rd + 15 : rd;
        float azf = (float)az * 0.09817477042468103f;   // 2*pi/64
        float phi = a_p[aidx] * cosf(azf) + b_p[aidx] * sinf(azf);
        float rn  = (float)rd * theta_max[b] * 0.015625f; // /64
        bias_tbl[j] = phi + a_r[ridx] * cosf(rn) + b_r[ridx] * sinf(rn);
    }
}

// ---------------- K1: QKV GEMM  [131072,256]x[256,768] -> bf16 qkv ----------
// wave = 64 rows (4 row-tiles), 32 MFMA per 8 B-loads, ping-pong B prefetch
__global__ __launch_bounds__(256, 2)
void qkv_gemm(const float* __restrict__ x, const unsigned short* __restrict__ w_qkv,
              const float* __restrict__ b_qkv, unsigned short* __restrict__ qkv)
{
    const int w    = threadIdx.x >> 6;
    const int lane = threadIdx.x & 63;
    const int quad = lane >> 4;
    const int l16  = lane & 15;
    const int mbase = blockIdx.x * 256 + w * 64;

    // A-frags: 4 row-tiles x full K=256 (fp32 -> bf16), 128 VGPRs
    bf16x8 af[4][8];
    #pragma unroll
    for (int rt = 0; rt < 4; ++rt) {
        const float* xrow = x + (size_t)(mbase + rt * 16 + l16) * 256;
        #pragma unroll
        for (int kk = 0; kk < 8; ++kk) {
            const float4* p = (const float4*)(xrow + kk * 32 + quad * 8);
            float4 v0 = p[0], v1 = p[1];
            bf16x8 a;
            a[0] = (short)f2bf(v0.x); a[1] = (short)f2bf(v0.y);
            a[2] = (short)f2bf(v0.z); a[3] = (short)f2bf(v0.w);
            a[4] = (short)f2bf(v1.x); a[5] = (short)f2bf(v1.y);
            a[6] = (short)f2bf(v1.z); a[7] = (short)f2bf(v1.w);
            af[rt][kk] = a;
        }
    }

    auto loadB = [&](bf16x8 (&b)[8], int nt) {
        const unsigned short* wp = w_qkv + (nt * 16 + l16) * 256 + quad * 8;
        #pragma unroll
        for (int kk = 0; kk < 8; ++kk)
            b[kk] = *(const bf16x8*)(wp + kk * 32);
    };
    auto tile = [&](const bf16x8 (&b)[8], int nt) {
        int ncol = nt * 16 + l16;
        float bias = b_qkv[ncol];
        f32x4 acc[4] = {{0,0,0,0},{0,0,0,0},{0,0,0,0},{0,0,0,0}};
        #pragma unroll
        for (int kk = 0; kk < 8; ++kk)
            #pragma unroll
            for (int rt = 0; rt < 4; ++rt)
                acc[rt] = __builtin_amdgcn_mfma_f32_16x16x32_bf16(af[rt][kk], b[kk], acc[rt], 0, 0, 0);
        #pragma unroll
        for (int rt = 0; rt < 4; ++rt)
            #pragma unroll
            for (int r = 0; r < 4; ++r)
                qkv[(size_t)(mbase + rt * 16 + quad * 4 + r) * 768 + ncol] = f2bf(acc[rt][r] + bias);
    };

    bf16x8 b0[8], b1[8];
    loadB(b0, 0);
    for (int nt = 0; nt < 48; nt += 2) {
        loadB(b1, nt + 1);
        tile(b0, nt);
        if (nt + 2 < 48) loadB(b0, nt + 2);
        tile(b1, nt + 1);
    }
}

// ---------------- K2: fused attention + proj --------------------------------
// S=QK^T(+bias), reg softmax, P->LDS, O=PV -> LDS, proj: out = O@Wp^T + b (f32)
__global__ __launch_bounds__(256, 2)
void attn_proj(const float* __restrict__ bias_tbl, const unsigned short* __restrict__ qkv,
               const unsigned short* __restrict__ w_proj, const float* __restrict__ proj_b,
               float* __restrict__ out)
{
    __shared__ unsigned short vT[256 * 64];   // [dim][tok], 16B-chunk XOR swizzled (32 KB)
    __shared__ unsigned short Pl[64 * 72];    // P [row][col+pad8]              (9 KB)
    __shared__ unsigned short Ol[64 * 264];   // attn out [tok][dim+pad8]       (33 KB)

    const int win   = blockIdx.x;
    const int batch = win >> 6;
    const size_t rowbase = (size_t)win * 64;
    const int tid  = threadIdx.x;
    const int w    = tid >> 6;
    const int lane = tid & 63;
    const int quad = lane >> 4;
    const int l16  = lane & 15;

    // ---- stage V transposed+swizzled; 64B-contiguous per 4-lane group ----
    {
        int tok  = tid >> 2;
        int part = tid & 3;
        const unsigned short* src = qkv + (rowbase + tok) * 768 + 512;
        #pragma unroll
        for (int jc = 0; jc < 8; ++jc) {
            int c = jc * 4 + part;                       // 16B chunk index 0..31
            bf16x8 v8 = *(const bf16x8*)(src + c * 8);
            #pragma unroll
            for (int e = 0; e < 8; ++e) {
                int d   = c * 8 + e;
                int swz = (((tok >> 3) ^ (d & 7)) << 3) | (tok & 7);
                vT[d * 64 + swz] = (unsigned short)v8[e];
            }
        }
    }

    // ---- Q frags (q pre-scaled in K1) ----
    bf16x8 qf[8];
    const unsigned short* qrow = qkv + (rowbase + w * 16 + l16) * 768;
    #pragma unroll
    for (int kk = 0; kk < 8; ++kk)
        qf[kk] = *(const bf16x8*)(qrow + kk * 32 + quad * 8);

    // ---- S = Q K^T ----
    f32x4 S[4];
    #pragma unroll
    for (int t = 0; t < 4; ++t) {
        const unsigned short* krow = qkv + (rowbase + t * 16 + l16) * 768 + 256 + quad * 8;
        f32x4 c = {0.f, 0.f, 0.f, 0.f};
        #pragma unroll
        for (int kk = 0; kk < 8; ++kk) {
            bf16x8 b = *(const bf16x8*)(krow + kk * 32);
            c = __builtin_amdgcn_mfma_f32_16x16x32_bf16(qf[kk], b, c, 0, 0, 0);
        }
        S[t] = c;
    }

    // ---- bias ----
    const float* bt = bias_tbl + batch * 4096 + (w * 16 + quad * 4) * 64 + l16;
    #pragma unroll
    for (int t = 0; t < 4; ++t)
        #pragma unroll
        for (int r = 0; r < 4; ++r)
            S[t][r] += bt[r * 64 + t * 16];

    // ---- softmax (registers, 16-lane reduction) ----
    float inv[4];
    #pragma unroll
    for (int r = 0; r < 4; ++r) {
        float m = fmaxf(fmaxf(S[0][r], S[1][r]), fmaxf(S[2][r], S[3][r]));
        #pragma unroll
        for (int off = 1; off < 16; off <<= 1)
            m = fmaxf(m, __shfl_xor(m, off, 64));
        float s = 0.f;
        #pragma unroll
        for (int t = 0; t < 4; ++t) { S[t][r] = __expf(S[t][r] - m); s += S[t][r]; }
        #pragma unroll
        for (int off = 1; off < 16; off <<= 1)
            s += __shfl_xor(s, off, 64);
        inv[r] = 1.0f / s;
    }

    // ---- P -> LDS ----
    #pragma unroll
    for (int t = 0; t < 4; ++t)
        #pragma unroll
        for (int r = 0; r < 4; ++r)
            Pl[(w * 16 + quad * 4 + r) * 72 + t * 16 + l16] = f2bf(S[t][r] * inv[r]);

    __syncthreads();   // vT + P ready

    // ---- O = P V -> LDS (bf16) ----
    #pragma unroll
    for (int n = 0; n < 16; ++n) {
        f32x4 c = {0.f, 0.f, 0.f, 0.f};
        int dim = n * 16 + l16;
        #pragma unroll
        for (int kk = 0; kk < 2; ++kk) {
            bf16x8 a = *(const bf16x8*)(&Pl[(w * 16 + l16) * 72 + kk * 32 + quad * 8]);
            int chunk = (kk * 4 + quad) ^ (dim & 7);
            bf16x8 b = *(const bf16x8*)(&vT[dim * 64 + chunk * 8]);
            c = __builtin_amdgcn_mfma_f32_16x16x32_bf16(a, b, c, 0, 0, 0);
        }
        #pragma unroll
        for (int r = 0; r < 4; ++r)
            Ol[(w * 16 + quad * 4 + r) * 264 + dim] = f2bf(c[r]);
    }

    __syncthreads();   // O ready

    // ---- proj: wave w computes all 64 rows x cols [w*64, w*64+64) ----
    bf16x8 af[4][8];
    #pragma unroll
    for (int rt = 0; rt < 4; ++rt)
        #pragma unroll
        for (int kk = 0; kk < 8; ++kk)
            af[rt][kk] = *(const bf16x8*)(&Ol[(rt * 16 + l16) * 264 + kk * 32 + quad * 8]);

    #pragma unroll
    for (int ntl = 0; ntl < 4; ++ntl) {
        int ncol = w * 64 + ntl * 16 + l16;
        const unsigned short* wp = w_proj + ncol * 256 + quad * 8;
        f32x4 acc[4] = {{0,0,0,0},{0,0,0,0},{0,0,0,0},{0,0,0,0}};
        #pragma unroll
        for (int kk = 0; kk < 8; ++kk) {
            bf16x8 b = *(const bf16x8*)(wp + kk * 32);
            #pragma unroll
            for (int rt = 0; rt < 4; ++rt)
                acc[rt] = __builtin_amdgcn_mfma_f32_16x16x32_bf16(af[rt][kk], b, acc[rt], 0, 0, 0);
        }
        float pb = proj_b[ncol];
        #pragma unroll
        for (int rt = 0; rt < 4; ++rt)
            #pragma unroll
            for (int r = 0; r < 4; ++r)
                out[(rowbase + rt * 16 + quad * 4 + r) * 256 + ncol] = acc[rt][r] + pb;
    }
}

// ---------------- launch ----------------------------------------------------
extern "C" void kernel_launch(void* const* d_in, const int* in_sizes, int n_in,
                              void* d_out, int out_size, void* d_ws, size_t ws_size,
                              hipStream_t stream)
{
    const float* x       = (const float*)d_in[0];
    const float* theta   = (const float*)d_in[1];
    const float* qkv_w   = (const float*)d_in[2];
    const float* qkv_b   = (const float*)d_in[3];
    const float* proj_w  = (const float*)d_in[4];
    const float* proj_b  = (const float*)d_in[5];
    const float* a_p     = (const float*)d_in[6];
    const float* b_p     = (const float*)d_in[7];
    const float* a_r     = (const float*)d_in[8];
    const float* b_r     = (const float*)d_in[9];
    const int*   radius  = (const int*)d_in[10];
    const int*   azimuth = (const int*)d_in[11];

    if (ws_size < (size_t)WS_NEED) return;

    char* ws = (char*)d_ws;
    unsigned short* w_qkv    = (unsigned short*)(ws + OFF_WQKV);
    unsigned short* w_proj   = (unsigned short*)(ws + OFF_WPROJ);
    float*          b_qkv    = (float*)(ws + OFF_BQKV);
    float*          bias_tbl = (float*)(ws + OFF_BIAS);
    unsigned short* qkv      = (unsigned short*)(ws + OFF_QKV);

    prep_kernel<<<1540, 256, 0, stream>>>(qkv_w, qkv_b, proj_w, theta,
                                          a_p, b_p, a_r, b_r, radius, azimuth,
                                          w_qkv, w_proj, b_qkv, bias_tbl);
    qkv_gemm<<<512, 256, 0, stream>>>(x, w_qkv, b_qkv, qkv);
    attn_proj<<<NWINDOWS, 256, 0, stream>>>(bias_tbl, qkv, w_proj, proj_b, (float*)d_out);
}

// Round 3
// 441.680 us; speedup vs baseline: 1.8005x; 1.0398x over previous
//
#include <hip/hip_runtime.h>
#include <stdint.h>

// ---- problem constants ----
#define NWINDOWS 2048          // B*N_WIN = 32*64
// qkv row layout: [768] = q(0:256) k(256:512) v(512:768)

typedef short bf16x8 __attribute__((ext_vector_type(8)));
typedef float f32x4  __attribute__((ext_vector_type(4)));

// workspace layout (bytes)
#define OFF_WQKV  0u           // 768*256 bf16  = 393216
#define OFF_WPROJ 393216u      // 256*256 bf16  = 131072
#define OFF_BQKV  524288u      // 768 f32       = 3072
#define OFF_BIAS  527360u      // 32*64*64 f32  = 524288
#define OFF_QKV   1051648u     // 131072*768 bf16 = 201326592
#define WS_NEED   202378240u

__device__ __forceinline__ unsigned short f2bf(float f) {
    union { float f; unsigned int u; } v; v.f = f;
    unsigned int u = v.u;
    u += 0x7FFFu + ((u >> 16) & 1u);     // RNE
    return (unsigned short)(u >> 16);
}

// ---------------- K0: prep (weights->bf16, fold q-scale, bias table) --------
__global__ __launch_bounds__(256)
void prep_kernel(const float* __restrict__ qkv_w, const float* __restrict__ qkv_b,
                 const float* __restrict__ proj_w, const float* __restrict__ theta_max,
                 const float* __restrict__ a_p, const float* __restrict__ b_p,
                 const float* __restrict__ a_r, const float* __restrict__ b_r,
                 const int* __restrict__ radius, const int* __restrict__ azimuth,
                 unsigned short* __restrict__ w_qkv, unsigned short* __restrict__ w_proj,
                 float* __restrict__ b_qkv, float* __restrict__ bias_tbl)
{
    int idx = blockIdx.x * 256 + threadIdx.x;
    const float scale = 0.0625f;                    // head_dim^-0.5 = 1/16
    if (idx < 196608) {                             // qkv_w -> bf16 (q rows scaled)
        int row = idx >> 8;
        float v = qkv_w[idx];
        if (row < 256) v *= scale;
        w_qkv[idx] = f2bf(v);
    } else if (idx < 196608 + 65536) {              // proj_w -> bf16
        int j = idx - 196608;
        w_proj[j] = f2bf(proj_w[j]);
    } else if (idx < 196608 + 65536 + 768) {        // qkv_b (scaled), kept f32
        int j = idx - (196608 + 65536);
        float v = qkv_b[j];
        if (j < 256) v *= scale;
        b_qkv[j] = v;
    } else if (idx < 196608 + 65536 + 768 + 131072) {  // bias_tbl[32][64][64]
        int j = idx - (196608 + 65536 + 768);
        int b  = j >> 12;
        int ij = j & 4095;
        int az = azimuth[ij];
        int rd = radius[ij];
        int aidx = az < 0 ? az + 15 : az;
        int ridx = rd < 0 ? rd + 15 : rd;
        float azf = (float)az * 0.09817477042468103f;   // 2*pi/64
        float phi = a_p[aidx] * cosf(azf) + b_p[aidx] * sinf(azf);
        float rn  = (float)rd * theta_max[b] * 0.015625f; // /64
        bias_tbl[j] = phi + a_r[ridx] * cosf(rn) + b_r[ridx] * sinf(rn);
    }
}

// ---------------- K1: QKV GEMM  [131072,256]x[256,768] -> bf16 qkv ----------
// wave = 64 rows, ping-pong B prefetch; epilogue: wave-private LDS transpose,
// flush every 8 col-tiles as 256B-contiguous rows (full-line HBM writes).
__global__ __launch_bounds__(256, 2)
void qkv_gemm(const float* __restrict__ x, const unsigned short* __restrict__ w_qkv,
              const float* __restrict__ b_qkv, unsigned short* __restrict__ qkv)
{
    // per-wave 64 rows x 128 cols bf16 pane; 136-col pitch (272B, 16B-mult, 4-bank skew)
    __shared__ unsigned short Cst[4 * 64 * 136];   // 69632 B -> 2 blocks/CU

    const int w    = threadIdx.x >> 6;
    const int lane = threadIdx.x & 63;
    const int quad = lane >> 4;
    const int l16  = lane & 15;
    const int mbase = blockIdx.x * 256 + w * 64;
    unsigned short* cw = Cst + w * (64 * 136);

    // A-frags: 4 row-tiles x full K=256 (fp32 -> bf16), 128 VGPRs
    bf16x8 af[4][8];
    #pragma unroll
    for (int rt = 0; rt < 4; ++rt) {
        const float* xrow = x + (size_t)(mbase + rt * 16 + l16) * 256;
        #pragma unroll
        for (int kk = 0; kk < 8; ++kk) {
            const float4* p = (const float4*)(xrow + kk * 32 + quad * 8);
            float4 v0 = p[0], v1 = p[1];
            bf16x8 a;
            a[0] = (short)f2bf(v0.x); a[1] = (short)f2bf(v0.y);
            a[2] = (short)f2bf(v0.z); a[3] = (short)f2bf(v0.w);
            a[4] = (short)f2bf(v1.x); a[5] = (short)f2bf(v1.y);
            a[6] = (short)f2bf(v1.z); a[7] = (short)f2bf(v1.w);
            af[rt][kk] = a;
        }
    }

    auto loadB = [&](bf16x8 (&b)[8], int nt) {
        const unsigned short* wp = w_qkv + (nt * 16 + l16) * 256 + quad * 8;
        #pragma unroll
        for (int kk = 0; kk < 8; ++kk)
            b[kk] = *(const bf16x8*)(wp + kk * 32);
    };

    // compute one 64x16 tile, deposit bf16 results into the wave's LDS pane
    auto tile = [&](const bf16x8 (&b)[8], int nt) {
        int ncol = nt * 16 + l16;
        float bias = b_qkv[ncol];
        f32x4 acc[4] = {{0,0,0,0},{0,0,0,0},{0,0,0,0},{0,0,0,0}};
        #pragma unroll
        for (int kk = 0; kk < 8; ++kk)
            #pragma unroll
            for (int rt = 0; rt < 4; ++rt)
                acc[rt] = __builtin_amdgcn_mfma_f32_16x16x32_bf16(af[rt][kk], b[kk], acc[rt], 0, 0, 0);
        int tcol = (nt & 7) * 16 + l16;            // col within 128-col group
        #pragma unroll
        for (int rt = 0; rt < 4; ++rt)
            #pragma unroll
            for (int r = 0; r < 4; ++r) {
                int row  = rt * 16 + quad * 4 + r;
                int colp = tcol ^ (((row >> 3) & 1) << 4);   // 16-col XOR swizzle
                cw[row * 136 + colp] = f2bf(acc[rt][r] + bias);
            }
    };

    // flush 64 rows x 128 cols: 16 x (ds_read_b128 + global_store_dwordx4),
    // 256B contiguous per row -> full-line HBM writes. Wave-private: no barrier.
    auto flushC = [&](int group) {
        int colbase = group * 128;
        int rowg  = lane >> 4;                     // 4 rows per store instr
        int chunk = lane & 15;                     // 16B chunk within 256B row run
        #pragma unroll
        for (int i = 0; i < 16; ++i) {
            int row = i * 4 + rowg;
            int cs  = chunk ^ (((row >> 3) & 1) << 1);   // undo 16-col swizzle
            bf16x8 v = *(const bf16x8*)(cw + row * 136 + cs * 8);
            *(bf16x8*)(qkv + (size_t)(mbase + row) * 768 + colbase + chunk * 8) = v;
        }
    };

    bf16x8 b0[8], b1[8];
    loadB(b0, 0);
    for (int nt = 0; nt < 48; nt += 2) {
        loadB(b1, nt + 1);
        tile(b0, nt);
        if (nt + 2 < 48) loadB(b0, nt + 2);
        tile(b1, nt + 1);
        if ((nt & 7) == 6) flushC(nt >> 3);
    }
}

// ---------------- K2: fused attention + proj --------------------------------
// S=QK^T(+bias), reg softmax, P->LDS, O=PV -> LDS, proj: out = O@Wp^T + b (f32)
__global__ __launch_bounds__(256, 2)
void attn_proj(const float* __restrict__ bias_tbl, const unsigned short* __restrict__ qkv,
               const unsigned short* __restrict__ w_proj, const float* __restrict__ proj_b,
               float* __restrict__ out)
{
    __shared__ unsigned short vT[256 * 64];   // [dim][tok], 16B-chunk XOR swizzled (32 KB)
    __shared__ unsigned short Pl[64 * 72];    // P [row][col+pad8]              (9 KB)
    __shared__ unsigned short Ol[64 * 264];   // attn out [tok][dim+pad8]       (33 KB)

    const int win   = blockIdx.x;
    const int batch = win >> 6;
    const size_t rowbase = (size_t)win * 64;
    const int tid  = threadIdx.x;
    const int w    = tid >> 6;
    const int lane = tid & 63;
    const int quad = lane >> 4;
    const int l16  = lane & 15;

    // ---- stage V transposed+swizzled; 64B-contiguous per 4-lane group ----
    {
        int tok  = tid >> 2;
        int part = tid & 3;
        const unsigned short* src = qkv + (rowbase + tok) * 768 + 512;
        #pragma unroll
        for (int jc = 0; jc < 8; ++jc) {
            int c = jc * 4 + part;                       // 16B chunk index 0..31
            bf16x8 v8 = *(const bf16x8*)(src + c * 8);
            #pragma unroll
            for (int e = 0; e < 8; ++e) {
                int d   = c * 8 + e;
                int swz = (((tok >> 3) ^ (d & 7)) << 3) | (tok & 7);
                vT[d * 64 + swz] = (unsigned short)v8[e];
            }
        }
    }

    // ---- Q frags (q pre-scaled in K1) ----
    bf16x8 qf[8];
    const unsigned short* qrow = qkv + (rowbase + w * 16 + l16) * 768;
    #pragma unroll
    for (int kk = 0; kk < 8; ++kk)
        qf[kk] = *(const bf16x8*)(qrow + kk * 32 + quad * 8);

    // ---- S = Q K^T ----
    f32x4 S[4];
    #pragma unroll
    for (int t = 0; t < 4; ++t) {
        const unsigned short* krow = qkv + (rowbase + t * 16 + l16) * 768 + 256 + quad * 8;
        f32x4 c = {0.f, 0.f, 0.f, 0.f};
        #pragma unroll
        for (int kk = 0; kk < 8; ++kk) {
            bf16x8 b = *(const bf16x8*)(krow + kk * 32);
            c = __builtin_amdgcn_mfma_f32_16x16x32_bf16(qf[kk], b, c, 0, 0, 0);
        }
        S[t] = c;
    }

    // ---- bias ----
    const float* bt = bias_tbl + batch * 4096 + (w * 16 + quad * 4) * 64 + l16;
    #pragma unroll
    for (int t = 0; t < 4; ++t)
        #pragma unroll
        for (int r = 0; r < 4; ++r)
            S[t][r] += bt[r * 64 + t * 16];

    // ---- softmax (registers, 16-lane reduction) ----
    float inv[4];
    #pragma unroll
    for (int r = 0; r < 4; ++r) {
        float m = fmaxf(fmaxf(S[0][r], S[1][r]), fmaxf(S[2][r], S[3][r]));
        #pragma unroll
        for (int off = 1; off < 16; off <<= 1)
            m = fmaxf(m, __shfl_xor(m, off, 64));
        float s = 0.f;
        #pragma unroll
        for (int t = 0; t < 4; ++t) { S[t][r] = __expf(S[t][r] - m); s += S[t][r]; }
        #pragma unroll
        for (int off = 1; off < 16; off <<= 1)
            s += __shfl_xor(s, off, 64);
        inv[r] = 1.0f / s;
    }

    // ---- P -> LDS ----
    #pragma unroll
    for (int t = 0; t < 4; ++t)
        #pragma unroll
        for (int r = 0; r < 4; ++r)
            Pl[(w * 16 + quad * 4 + r) * 72 + t * 16 + l16] = f2bf(S[t][r] * inv[r]);

    __syncthreads();   // vT + P ready

    // ---- O = P V -> LDS (bf16) ----
    #pragma unroll
    for (int n = 0; n < 16; ++n) {
        f32x4 c = {0.f, 0.f, 0.f, 0.f};
        int dim = n * 16 + l16;
        #pragma unroll
        for (int kk = 0; kk < 2; ++kk) {
            bf16x8 a = *(const bf16x8*)(&Pl[(w * 16 + l16) * 72 + kk * 32 + quad * 8]);
            int chunk = (kk * 4 + quad) ^ (dim & 7);
            bf16x8 b = *(const bf16x8*)(&vT[dim * 64 + chunk * 8]);
            c = __builtin_amdgcn_mfma_f32_16x16x32_bf16(a, b, c, 0, 0, 0);
        }
        #pragma unroll
        for (int r = 0; r < 4; ++r)
            Ol[(w * 16 + quad * 4 + r) * 264 + dim] = f2bf(c[r]);
    }

    __syncthreads();   // O ready

    // ---- proj: wave w computes all 64 rows x cols [w*64, w*64+64) ----
    bf16x8 af[4][8];
    #pragma unroll
    for (int rt = 0; rt < 4; ++rt)
        #pragma unroll
        for (int kk = 0; kk < 8; ++kk)
            af[rt][kk] = *(const bf16x8*)(&Ol[(rt * 16 + l16) * 264 + kk * 32 + quad * 8]);

    #pragma unroll
    for (int ntl = 0; ntl < 4; ++ntl) {
        int ncol = w * 64 + ntl * 16 + l16;
        const unsigned short* wp = w_proj + ncol * 256 + quad * 8;
        f32x4 acc[4] = {{0,0,0,0},{0,0,0,0},{0,0,0,0},{0,0,0,0}};
        #pragma unroll
        for (int kk = 0; kk < 8; ++kk) {
            bf16x8 b = *(const bf16x8*)(wp + kk * 32);
            #pragma unroll
            for (int rt = 0; rt < 4; ++rt)
                acc[rt] = __builtin_amdgcn_mfma_f32_16x16x32_bf16(af[rt][kk], b, acc[rt], 0, 0, 0);
        }
        float pb = proj_b[ncol];
        #pragma unroll
        for (int rt = 0; rt < 4; ++rt)
            #pragma unroll
            for (int r = 0; r < 4; ++r)
                out[(rowbase + rt * 16 + quad * 4 + r) * 256 + ncol] = acc[rt][r] + pb;
    }
}

// ---------------- launch ----------------------------------------------------
extern "C" void kernel_launch(void* const* d_in, const int* in_sizes, int n_in,
                              void* d_out, int out_size, void* d_ws, size_t ws_size,
                              hipStream_t stream)
{
    const float* x       = (const float*)d_in[0];
    const float* theta   = (const float*)d_in[1];
    const float* qkv_w   = (const float*)d_in[2];
    const float* qkv_b   = (const float*)d_in[3];
    const float* proj_w  = (const float*)d_in[4];
    const float* proj_b  = (const float*)d_in[5];
    const float* a_p     = (const float*)d_in[6];
    const float* b_p     = (const float*)d_in[7];
    const float* a_r     = (const float*)d_in[8];
    const float* b_r     = (const float*)d_in[9];
    const int*   radius  = (const int*)d_in[10];
    const int*   azimuth = (const int*)d_in[11];

    if (ws_size < (size_t)WS_NEED) return;

    char* ws = (char*)d_ws;
    unsigned short* w_qkv    = (unsigned short*)(ws + OFF_WQKV);
    unsigned short* w_proj   = (unsigned short*)(ws + OFF_WPROJ);
    float*          b_qkv    = (float*)(ws + OFF_BQKV);
    float*          bias_tbl = (float*)(ws + OFF_BIAS);
    unsigned short* qkv      = (unsigned short*)(ws + OFF_QKV);

    prep_kernel<<<1540, 256, 0, stream>>>(qkv_w, qkv_b, proj_w, theta,
                                          a_p, b_p, a_r, b_r, radius, azimuth,
                                          w_qkv, w_proj, b_qkv, bias_tbl);
    qkv_gemm<<<512, 256, 0, stream>>>(x, w_qkv, b_qkv, qkv);
    attn_proj<<<NWINDOWS, 256, 0, stream>>>(bias_tbl, qkv, w_proj, proj_b, (float*)d_out);
}